// Round 7
// baseline (390.246 us; speedup 1.0000x reference)
//
#include <hip/hip_runtime.h>
#include <hip/hip_bf16.h>

#define KK 32
#define DIN 128
#define DOUT 32
#define NVEC (KK * DOUT)        // 1024 floats per node
#define MBKT 64                 // bucket slots per row == wave size
#define OCAP 4096               // overflow capacity (never used for Poisson(16))

typedef float        vf4    __attribute__((ext_vector_type(4)));
typedef unsigned int vu4    __attribute__((ext_vector_type(4)));
typedef short        bf16x8 __attribute__((ext_vector_type(8)));

__device__ __forceinline__ float bfu2f(unsigned int u) {
    return __uint_as_float(u << 16);
}
__device__ __forceinline__ unsigned int f2bfu(float f) {
    __hip_bfloat16 b = __float2bfloat16(f);
    return *(unsigned short*)&b;
}

// ---------------- K2: zero cursor[N]+ocnt AND pack W fragments once ---------
// Block 0 additionally converts W (128x32 f32, 16KB) into the exact per-lane
// bf16x8 MFMA fragment order: wfrag[(nt*4+ks)*64 + lane][j] = bf16(W[k][n]),
// k = ks*32 + (lane>>4)*8 + j, n = nt*16 + (lane&15).
__global__ __launch_bounds__(256) void prep_kernel(
    int* __restrict__ p, int n,
    const float* __restrict__ w, unsigned short* __restrict__ wfrag)
{
    int i = blockIdx.x * 256 + threadIdx.x;
    if (i < n) p[i] = 0;
    if (blockIdx.x == 0) {
        for (int item = threadIdx.x; item < 512; item += 256) {
            int lane = item & 63;
            int fk   = item >> 6;          // nt*4 + ks
            int nt   = fk >> 2, ks = fk & 3;
            int q    = lane >> 4, lm = lane & 15;
            #pragma unroll
            for (int j = 0; j < 8; ++j) {
                int k = ks * 32 + q * 8 + j;
                wfrag[(size_t)item * 8 + j] =
                    (unsigned short)f2bfu(w[k * DOUT + nt * 16 + lm]);
            }
        }
    }
}

// ---------------- K1 (fused): fill_bucket (blocks < FB) + MFMA gemm ----------
// gemm: 16x16x32 bf16 MFMA, A straight from global in fragment layout
// (NONTEMPORAL: x is read exactly once; keep cache lines for h, which K3
// re-reads ~16x), B fragments from the precomputed wfrag table. C stored
// DIRECTLY from fragments into a column-permuted h layout:
//   h[row][2q]   = col q      (acc0)
//   h[row][2q+1] = col q+16   (acc1)
// 1 tile (16 rows) per wave: 20000 waves -> full TLP for latency hiding.
__global__ __launch_bounds__(256) void gemm_fill_kernel(
    const float* __restrict__ x, const unsigned short* __restrict__ wfrag,
    unsigned short* __restrict__ h,
    const int* __restrict__ erow, const int* __restrict__ ecol,
    const float* __restrict__ eval, int* __restrict__ cursor,
    uint2* __restrict__ bedge,
    int* __restrict__ ocnt, int* __restrict__ orow,
    int* __restrict__ ocol, float* __restrict__ oval,
    int E, int FB)
{
    const int tid = threadIdx.x;

    if (blockIdx.x < (unsigned)FB) {
        // ---- fill part: first in dispatch queue -> overlaps gemm's start ----
        int i = blockIdx.x * 256 + tid;
        if (i >= E) return;
        int r = __builtin_nontemporal_load(erow + i);
        int p = atomicAdd(&cursor[r], 1);
        if (p < MBKT) {
            uint2 e;
            e.x = (unsigned int)__builtin_nontemporal_load(ecol + i);
            e.y = __float_as_uint(__builtin_nontemporal_load(eval + i));
            bedge[r * MBKT + p] = e;
        } else {
            int q = atomicAdd(ocnt, 1);
            if (q < OCAP) {
                orow[q] = r;
                ocol[q] = ecol[i];
                oval[q] = eval[i];
            }
        }
        return;
    }

    // ---- gemm part ----
    const int lane = tid & 63;
    const int wid  = tid >> 6;
    const int q    = lane >> 4;           // quad 0..3
    const int lm   = lane & 15;

    // B fragments: 8 coalesced 16B loads from the 8KB wfrag table (L2-hot).
    bf16x8 bf[2][4];
    {
        const bf16x8* wf = (const bf16x8*)wfrag;
        #pragma unroll
        for (int nt = 0; nt < 2; ++nt)
            #pragma unroll
            for (int ks = 0; ks < 4; ++ks)
                bf[nt][ks] = wf[(nt * 4 + ks) * 64 + lane];
    }

    const int tile = (blockIdx.x - FB) * 4 + wid;   // 0..19999
    const int r0   = tile * 16;
    const float* xrow = x + (size_t)(r0 + lm) * DIN + q * 8;

    vf4 acc0 = {0.f, 0.f, 0.f, 0.f};
    vf4 acc1 = {0.f, 0.f, 0.f, 0.f};

    #pragma unroll
    for (int ks = 0; ks < 4; ++ks) {
        vf4 a0 = __builtin_nontemporal_load((const vf4*)(xrow + ks * 32));
        vf4 a1 = __builtin_nontemporal_load((const vf4*)(xrow + ks * 32 + 4));
        bf16x8 af;
        af[0] = (short)f2bfu(a0.x); af[1] = (short)f2bfu(a0.y);
        af[2] = (short)f2bfu(a0.z); af[3] = (short)f2bfu(a0.w);
        af[4] = (short)f2bfu(a1.x); af[5] = (short)f2bfu(a1.y);
        af[6] = (short)f2bfu(a1.z); af[7] = (short)f2bfu(a1.w);
        acc0 = __builtin_amdgcn_mfma_f32_16x16x32_bf16(af, bf[0][ks], acc0, 0, 0, 0);
        acc1 = __builtin_amdgcn_mfma_f32_16x16x32_bf16(af, bf[1][ks], acc1, 0, 0, 0);
    }

    // direct C store: row=(lane>>4)*4+q2 (C/D mapping), permuted cols
    #pragma unroll
    for (int q2 = 0; q2 < 4; ++q2) {
        unsigned int pk = f2bfu(acc0[q2]) | (f2bfu(acc1[q2]) << 16);
        *(unsigned int*)(h + (size_t)(r0 + q * 4 + q2) * DOUT + lm * 2) = pk;
    }
}

// ---------------- K3: per-node gather-accumulate + ReLU ----------------------
// R5 structure (best known). DIAGNOSTIC ROUND: this kernel is launched 3x
// (idempotent: re-reads unchanged h/bedge/cursor, rewrites identical out).
// dur_delta = 2 x agg_dur resolves the gemm/agg split that top-5-only
// rocprof visibility hides (all 5 slots are ~97us harness poison fills).
__global__ __launch_bounds__(128) void agg_kernel(
    const unsigned short* __restrict__ h, const int* __restrict__ cursor,
    const uint2* __restrict__ bedge,
    const int* __restrict__ ocnt, const int* __restrict__ orow,
    const int* __restrict__ ocol, const float* __restrict__ oval,
    float* __restrict__ out)
{
    const int lt   = threadIdx.x;        // 0..127: owns 8 h-positions (16B)
    const int lane = lt & 63;
    const int r    = blockIdx.x;

    const int deg  = cursor[r];
    const int degb = deg < MBKT ? deg : MBKT;
    const int on0  = *ocnt;              // issued early; cold path below

    int   ec = 0;
    float ev = 0.f;
    if (lane < degb) {
        uint2 e = bedge[r * MBKT + lane];
        ec = (int)e.x;
        ev = __uint_as_float(e.y);
    }

    float acc[8];
    #pragma unroll
    for (int q = 0; q < 8; ++q) acc[q] = 0.f;

    #pragma unroll 8
    for (int j = 0; j < degb; ++j) {
        int   c = __shfl(ec, j, 64);
        float v = __shfl(ev, j, 64);
        vu4 p = *(const vu4*)(h + (size_t)c * NVEC + lt * 8);
        acc[0] += v * bfu2f(p.x & 0xffffu);
        acc[1] += v * bfu2f(p.x >> 16);
        acc[2] += v * bfu2f(p.y & 0xffffu);
        acc[3] += v * bfu2f(p.y >> 16);
        acc[4] += v * bfu2f(p.z & 0xffffu);
        acc[5] += v * bfu2f(p.z >> 16);
        acc[6] += v * bfu2f(p.w & 0xffffu);
        acc[7] += v * bfu2f(p.w >> 16);
    }

    // cold overflow path (correctness only; empty for this graph)
    if (on0 > 0) {
        int on = on0 > OCAP ? OCAP : on0;
        for (int q = 0; q < on; ++q) {
            if (orow[q] == r) {
                int   c = ocol[q];
                float v = oval[q];
                vu4 p = *(const vu4*)(h + (size_t)c * NVEC + lt * 8);
                acc[0] += v * bfu2f(p.x & 0xffffu);
                acc[1] += v * bfu2f(p.x >> 16);
                acc[2] += v * bfu2f(p.y & 0xffffu);
                acc[3] += v * bfu2f(p.y >> 16);
                acc[4] += v * bfu2f(p.z & 0xffffu);
                acc[5] += v * bfu2f(p.z >> 16);
                acc[6] += v * bfu2f(p.w & 0xffffu);
                acc[7] += v * bfu2f(p.w >> 16);
            }
        }
    }

    // unpermute: even accs -> cols 4*(lt&3)..+3 ; odd accs -> +16
    vf4 oA, oB;
    oA.x = fmaxf(acc[0], 0.f); oA.y = fmaxf(acc[2], 0.f);
    oA.z = fmaxf(acc[4], 0.f); oA.w = fmaxf(acc[6], 0.f);
    oB.x = fmaxf(acc[1], 0.f); oB.y = fmaxf(acc[3], 0.f);
    oB.z = fmaxf(acc[5], 0.f); oB.w = fmaxf(acc[7], 0.f);
    float* obase = out + (size_t)r * NVEC + (lt >> 2) * 32 + (lt & 3) * 4;
    __builtin_nontemporal_store(oA, (vf4*)obase);        // cols c..c+3
    __builtin_nontemporal_store(oB, (vf4*)(obase + 16)); // cols 16+c..+3
}

extern "C" void kernel_launch(void* const* d_in, const int* in_sizes, int n_in,
                              void* d_out, int out_size, void* d_ws, size_t ws_size,
                              hipStream_t stream)
{
    const float* x    = (const float*)d_in[0];
    const float* w    = (const float*)d_in[1];
    const int*   erow = (const int*)d_in[2];
    const int*   ecol = (const int*)d_in[3];
    const float* eval = (const float*)d_in[4];
    float* out = (float*)d_out;

    const int E = in_sizes[2];
    const int N = in_sizes[0] / (KK * DIN);
    const int R = N * KK;

    char* ws = (char*)d_ws;
    size_t off = 0;
    auto take = [&](size_t bytes) {
        void* p = ws + off;
        off += (bytes + 15) & ~(size_t)15;
        return p;
    };
    unsigned short* h = (unsigned short*)take((size_t)R * DOUT * sizeof(unsigned short));
    int*   cursor = (int*)take((size_t)(N + 1) * sizeof(int)); // [N]=oflow_cnt
    uint2* bedge  = (uint2*)take((size_t)N * MBKT * sizeof(uint2));
    int*   orow   = (int*)take((size_t)OCAP * sizeof(int));
    int*   ocol   = (int*)take((size_t)OCAP * sizeof(int));
    float* oval   = (float*)take((size_t)OCAP * sizeof(float));
    unsigned short* wfrag = (unsigned short*)take((size_t)512 * 8 * sizeof(unsigned short));
    int*   ocnt   = cursor + N;
    (void)ws_size;

    const int FB = (E + 255) / 256;       // fill blocks (first in queue)
    const int GB = (R / 16) / 4;          // 1 tile/wave, 4 waves/block

    prep_kernel<<<(N + 1 + 255) / 256, 256, 0, stream>>>(cursor, N + 1, w, wfrag);
    gemm_fill_kernel<<<FB + GB, 256, 0, stream>>>(
        x, wfrag, h, erow, ecol, eval, cursor, bedge, ocnt, orow, ocol, oval, E, FB);
    // DIAGNOSTIC: agg x3 (idempotent). dur - dur_R5 = 2 x agg_dur.
    agg_kernel<<<N, 128, 0, stream>>>(
        h, cursor, bedge, ocnt, orow, ocol, oval, out);
    agg_kernel<<<N, 128, 0, stream>>>(
        h, cursor, bedge, ocnt, orow, ocol, oval, out);
    agg_kernel<<<N, 128, 0, stream>>>(
        h, cursor, bedge, ocnt, orow, ocol, oval, out);
}

// Round 8
// 299.505 us; speedup vs baseline: 1.3030x; 1.3030x over previous
//
#include <hip/hip_runtime.h>
#include <hip/hip_bf16.h>

#define KK 32
#define DIN 128
#define DOUT 32
#define NVEC (KK * DOUT)        // 1024 floats per node
#define MBKT 64                 // bucket slots per row == wave size
#define OCAP 4096               // overflow capacity (never used for Poisson(16))

typedef float        vf4    __attribute__((ext_vector_type(4)));
typedef unsigned int vu4    __attribute__((ext_vector_type(4)));
typedef short        bf16x8 __attribute__((ext_vector_type(8)));

__device__ __forceinline__ float bfu2f(unsigned int u) {
    return __uint_as_float(u << 16);
}
__device__ __forceinline__ unsigned int f2bfu(float f) {
    __hip_bfloat16 b = __float2bfloat16(f);
    return *(unsigned short*)&b;
}

// ---------------- K2: zero cursor[N]+ocnt AND pack W fragments once ---------
__global__ __launch_bounds__(256) void prep_kernel(
    int* __restrict__ p, int n,
    const float* __restrict__ w, unsigned short* __restrict__ wfrag)
{
    int i = blockIdx.x * 256 + threadIdx.x;
    if (i < n) p[i] = 0;
    if (blockIdx.x == 0) {
        for (int item = threadIdx.x; item < 512; item += 256) {
            int lane = item & 63;
            int fk   = item >> 6;          // nt*4 + ks
            int nt   = fk >> 2, ks = fk & 3;
            int q    = lane >> 4, lm = lane & 15;
            #pragma unroll
            for (int j = 0; j < 8; ++j) {
                int k = ks * 32 + q * 8 + j;
                wfrag[(size_t)item * 8 + j] =
                    (unsigned short)f2bfu(w[k * DOUT + nt * 16 + lm]);
            }
        }
    }
}

// ---------------- K1 (fused): fill_bucket (blocks < FB) + MFMA gemm ----------
// A-path restructured (R7 diagnosis: TA/coalescer-bound, ~40us of half-used
// 64B line-requests). Now: stage the wave's 16x128 f32 tile into LDS with
// CONTIGUOUS dwordx4 loads (16 fully-used lines per instr, ~4x fewer TA
// line-requests), fragments via swizzled ds_read_b128.
//   swizzle: lds 16B-slot t of row r holds x slot t^(r&7) (source-side XOR,
//   dest linear). ds_read at slot (2q+8ks)^(lm&7): per 8-lane group all 32
//   banks hit exactly once -> BW-optimal, no conflicts.
// Tile is WAVE-PRIVATE (8KB; 32KB/block) -> no __syncthreads needed;
// compiler inserts lgkmcnt for the ds_write->ds_read dependency.
// Fragment values bit-identical to the direct-load version.
__global__ __launch_bounds__(256) void gemm_fill_kernel(
    const float* __restrict__ x, const unsigned short* __restrict__ wfrag,
    unsigned short* __restrict__ h,
    const int* __restrict__ erow, const int* __restrict__ ecol,
    const float* __restrict__ eval, int* __restrict__ cursor,
    uint2* __restrict__ bedge,
    int* __restrict__ ocnt, int* __restrict__ orow,
    int* __restrict__ ocol, float* __restrict__ oval,
    int E, int FB)
{
    __shared__ float xtile[4][16 * DIN];   // 4 waves x 16 rows x 128 f32 = 32KB
    const int tid = threadIdx.x;

    if (blockIdx.x < (unsigned)FB) {
        // ---- fill part: first in dispatch queue -> overlaps gemm's start ----
        int i = blockIdx.x * 256 + tid;
        if (i >= E) return;
        int r = __builtin_nontemporal_load(erow + i);
        int p = atomicAdd(&cursor[r], 1);
        if (p < MBKT) {
            uint2 e;
            e.x = (unsigned int)__builtin_nontemporal_load(ecol + i);
            e.y = __float_as_uint(__builtin_nontemporal_load(eval + i));
            bedge[r * MBKT + p] = e;
        } else {
            int q = atomicAdd(ocnt, 1);
            if (q < OCAP) {
                orow[q] = r;
                ocol[q] = ecol[i];
                oval[q] = eval[i];
            }
        }
        return;
    }

    // ---- gemm part ----
    const int lane = tid & 63;
    const int wid  = tid >> 6;
    const int q    = lane >> 4;           // quad 0..3
    const int lm   = lane & 15;
    const int lm7  = lm & 7;

    // B fragments: 8 coalesced 16B loads from the 8KB wfrag table (L1-hot).
    bf16x8 bf[2][4];
    {
        const bf16x8* wf = (const bf16x8*)wfrag;
        #pragma unroll
        for (int nt = 0; nt < 2; ++nt)
            #pragma unroll
            for (int ks = 0; ks < 4; ++ks)
                bf[nt][ks] = wf[(nt * 4 + ks) * 64 + lane];
    }

    const int tile = (blockIdx.x - FB) * 4 + wid;   // 0..19999
    const int r0   = tile * 16;
    float* lt = xtile[wid];

    // stage 16 rows with contiguous dwordx4 (2 rows per instr), swizzled src:
    // lds[rl][slot s] = x[rl][slot s ^ (rl&7)]  (slots are 16B)
    #pragma unroll
    for (int i = 0; i < 8; ++i) {
        int rl = 2 * i + (lane >> 5);          // local row 0..15
        int s  = lane & 31;                    // 16B slot in row
        int ss = s ^ (rl & 7);                 // pre-swizzled source slot
        vf4 v = *(const vf4*)(x + (size_t)(r0 + rl) * DIN + ss * 4);
        *(vf4*)(lt + rl * DIN + s * 4) = v;
    }

    vf4 acc0 = {0.f, 0.f, 0.f, 0.f};
    vf4 acc1 = {0.f, 0.f, 0.f, 0.f};

    #pragma unroll
    for (int ks = 0; ks < 4; ++ks) {
        int u0 = (2 * q + 8 * ks) ^ lm7;       // swizzled slot of floats q*8+ks*32..+3
        int u1 = u0 ^ 1;                       // .. and +4..+7
        vf4 a0 = *(const vf4*)(lt + lm * DIN + u0 * 4);
        vf4 a1 = *(const vf4*)(lt + lm * DIN + u1 * 4);
        bf16x8 af;
        af[0] = (short)f2bfu(a0.x); af[1] = (short)f2bfu(a0.y);
        af[2] = (short)f2bfu(a0.z); af[3] = (short)f2bfu(a0.w);
        af[4] = (short)f2bfu(a1.x); af[5] = (short)f2bfu(a1.y);
        af[6] = (short)f2bfu(a1.z); af[7] = (short)f2bfu(a1.w);
        acc0 = __builtin_amdgcn_mfma_f32_16x16x32_bf16(af, bf[0][ks], acc0, 0, 0, 0);
        acc1 = __builtin_amdgcn_mfma_f32_16x16x32_bf16(af, bf[1][ks], acc1, 0, 0, 0);
    }

    // direct C store: row=(lane>>4)*4+q2 (C/D mapping), permuted cols
    #pragma unroll
    for (int q2 = 0; q2 < 4; ++q2) {
        unsigned int pk = f2bfu(acc0[q2]) | (f2bfu(acc1[q2]) << 16);
        *(unsigned int*)(h + (size_t)(r0 + q * 4 + q2) * DOUT + lm * 2) = pk;
    }
}

// ---------------- K3: per-node gather-accumulate + ReLU ----------------------
// R5 structure (best known): 1 row per 128-thread block, dwordx4 gather,
// bedge loaded once, unroll 8.
__global__ __launch_bounds__(128) void agg_kernel(
    const unsigned short* __restrict__ h, const int* __restrict__ cursor,
    const uint2* __restrict__ bedge,
    const int* __restrict__ ocnt, const int* __restrict__ orow,
    const int* __restrict__ ocol, const float* __restrict__ oval,
    float* __restrict__ out)
{
    const int lt   = threadIdx.x;        // 0..127: owns 8 h-positions (16B)
    const int lane = lt & 63;
    const int r    = blockIdx.x;

    const int deg  = cursor[r];
    const int degb = deg < MBKT ? deg : MBKT;
    const int on0  = *ocnt;              // issued early; cold path below

    int   ec = 0;
    float ev = 0.f;
    if (lane < degb) {
        uint2 e = bedge[r * MBKT + lane];
        ec = (int)e.x;
        ev = __uint_as_float(e.y);
    }

    float acc[8];
    #pragma unroll
    for (int q = 0; q < 8; ++q) acc[q] = 0.f;

    #pragma unroll 8
    for (int j = 0; j < degb; ++j) {
        int   c = __shfl(ec, j, 64);
        float v = __shfl(ev, j, 64);
        vu4 p = *(const vu4*)(h + (size_t)c * NVEC + lt * 8);
        acc[0] += v * bfu2f(p.x & 0xffffu);
        acc[1] += v * bfu2f(p.x >> 16);
        acc[2] += v * bfu2f(p.y & 0xffffu);
        acc[3] += v * bfu2f(p.y >> 16);
        acc[4] += v * bfu2f(p.z & 0xffffu);
        acc[5] += v * bfu2f(p.z >> 16);
        acc[6] += v * bfu2f(p.w & 0xffffu);
        acc[7] += v * bfu2f(p.w >> 16);
    }

    // cold overflow path (correctness only; empty for this graph)
    if (on0 > 0) {
        int on = on0 > OCAP ? OCAP : on0;
        for (int q = 0; q < on; ++q) {
            if (orow[q] == r) {
                int   c = ocol[q];
                float v = oval[q];
                vu4 p = *(const vu4*)(h + (size_t)c * NVEC + lt * 8);
                acc[0] += v * bfu2f(p.x & 0xffffu);
                acc[1] += v * bfu2f(p.x >> 16);
                acc[2] += v * bfu2f(p.y & 0xffffu);
                acc[3] += v * bfu2f(p.y >> 16);
                acc[4] += v * bfu2f(p.z & 0xffffu);
                acc[5] += v * bfu2f(p.z >> 16);
                acc[6] += v * bfu2f(p.w & 0xffffu);
                acc[7] += v * bfu2f(p.w >> 16);
            }
        }
    }

    // unpermute: even accs -> cols 4*(lt&3)..+3 ; odd accs -> +16
    vf4 oA, oB;
    oA.x = fmaxf(acc[0], 0.f); oA.y = fmaxf(acc[2], 0.f);
    oA.z = fmaxf(acc[4], 0.f); oA.w = fmaxf(acc[6], 0.f);
    oB.x = fmaxf(acc[1], 0.f); oB.y = fmaxf(acc[3], 0.f);
    oB.z = fmaxf(acc[5], 0.f); oB.w = fmaxf(acc[7], 0.f);
    float* obase = out + (size_t)r * NVEC + (lt >> 2) * 32 + (lt & 3) * 4;
    __builtin_nontemporal_store(oA, (vf4*)obase);        // cols c..c+3
    __builtin_nontemporal_store(oB, (vf4*)(obase + 16)); // cols 16+c..+3
}

extern "C" void kernel_launch(void* const* d_in, const int* in_sizes, int n_in,
                              void* d_out, int out_size, void* d_ws, size_t ws_size,
                              hipStream_t stream)
{
    const float* x    = (const float*)d_in[0];
    const float* w    = (const float*)d_in[1];
    const int*   erow = (const int*)d_in[2];
    const int*   ecol = (const int*)d_in[3];
    const float* eval = (const float*)d_in[4];
    float* out = (float*)d_out;

    const int E = in_sizes[2];
    const int N = in_sizes[0] / (KK * DIN);
    const int R = N * KK;

    char* ws = (char*)d_ws;
    size_t off = 0;
    auto take = [&](size_t bytes) {
        void* p = ws + off;
        off += (bytes + 15) & ~(size_t)15;
        return p;
    };
    unsigned short* h = (unsigned short*)take((size_t)R * DOUT * sizeof(unsigned short));
    int*   cursor = (int*)take((size_t)(N + 1) * sizeof(int)); // [N]=oflow_cnt
    uint2* bedge  = (uint2*)take((size_t)N * MBKT * sizeof(uint2));
    int*   orow   = (int*)take((size_t)OCAP * sizeof(int));
    int*   ocol   = (int*)take((size_t)OCAP * sizeof(int));
    float* oval   = (float*)take((size_t)OCAP * sizeof(float));
    unsigned short* wfrag = (unsigned short*)take((size_t)512 * 8 * sizeof(unsigned short));
    int*   ocnt   = cursor + N;
    (void)ws_size;

    const int FB = (E + 255) / 256;       // fill blocks (first in queue)
    const int GB = (R / 16) / 4;          // 1 tile/wave, 4 waves/block

    prep_kernel<<<(N + 1 + 255) / 256, 256, 0, stream>>>(cursor, N + 1, w, wfrag);
    gemm_fill_kernel<<<FB + GB, 256, 0, stream>>>(
        x, wfrag, h, erow, ecol, eval, cursor, bedge, ocnt, orow, ocol, oval, E, FB);
    agg_kernel<<<N, 128, 0, stream>>>(
        h, cursor, bedge, ocnt, orow, ocol, oval, out);
}